// Round 5
// baseline (34.207 us; speedup 1.0000x reference)
//
#include <hip/hip_runtime.h>

// Volume rendering (NeRF-style) for B=8, N=8192, S=128.
// One 16-lane segment per ray (4 rays/wave, 16 rays/block); lane owns 8
// consecutive samples. rgbs (96 MB, the bulk of read traffic) is staged
// through LDS with fully-coalesced global loads and a padded layout so
// the per-lane strided reads are bank-conflict-free.

namespace {
constexpr int kB = 8;
constexpr int kN = 8192;
constexpr int kS = 128;
constexpr int kRays = kB * kN;          // 65536
constexpr int kRaysPerBlock = 16;       // block = 256 threads, 4 waves

__global__ __launch_bounds__(256) void volrender_kernel(
    const float* __restrict__ dens,     // [rays, S]
    const float* __restrict__ rgbs,     // [rays, S, 3]
    const float* __restrict__ tvals,    // [rays, S]
    float* __restrict__ out_rgb,        // [rays, 3]
    float* __restrict__ out_w,          // [rays, S]
    float* __restrict__ out_depth,     // [rays]
    float* __restrict__ out_acc)        // [rays]
{
    const int tid  = threadIdx.x;
    const int lane = tid & 63;
    const int wave = tid >> 6;
    const int seg  = lane & 15;                    // lane within ray segment
    const int rayLocal = wave * 4 + (lane >> 4);   // 0..15 within block
    const int ray  = blockIdx.x * kRaysPerBlock + rayLocal;

    // ---- Stage rgbs through LDS ----
    // Block's rgb = 16 rays * 384 floats = 1536 float4. Linear float4 index
    // idx maps to (chunk = idx/6, j = idx%6) where chunk = rayLocal*16+seg.
    // LDS layout pads each chunk to 7 float4s -> seg-stride 28 words mod 32
    // => max 2 lanes/bank on reads (free).
    __shared__ float4 srgb[kRaysPerBlock * 16 * 7];   // 1792 float4 = 28 KB

    const float4* grgb =
        (const float4*)(rgbs + (long)blockIdx.x * kRaysPerBlock * kS * 3);
    #pragma unroll
    for (int j = 0; j < 6; ++j) {
        const int idx = tid + 256 * j;             // 0..1535, coalesced
        srgb[(idx / 6) * 7 + (idx % 6)] = grgb[idx];
    }

    const int base = ray * kS + seg * 8;           // first of lane's 8 samples

    const float4 ta = *(const float4*)(tvals + base);
    const float4 tb = *(const float4*)(tvals + base + 4);
    const float4 sa = *(const float4*)(dens  + base);
    const float4 sb = *(const float4*)(dens  + base + 4);

    __syncthreads();

    const int cbase = (rayLocal * 16 + seg) * 7;
    const float4 q0 = srgb[cbase + 0];
    const float4 q1 = srgb[cbase + 1];
    const float4 q2 = srgb[cbase + 2];
    const float4 q3 = srgb[cbase + 3];
    const float4 q4 = srgb[cbase + 4];
    const float4 q5 = srgb[cbase + 5];

    // deltas; last sample of each ray -> 1e10
    const float t_next = __shfl_down(ta.x, 1);     // next lane's first t
    const float d0 = ta.y - ta.x;
    const float d1 = ta.z - ta.y;
    const float d2 = ta.w - ta.z;
    const float d3 = tb.x - ta.w;
    const float d4 = tb.y - tb.x;
    const float d5 = tb.z - tb.y;
    const float d6 = tb.w - tb.z;
    const float d7 = (seg == 15) ? 1e10f : (t_next - tb.w);

    // e = exp(-sigma*delta); alpha = 1-e; cumprod factor f = e + EPS
    const float e0 = __expf(-sa.x * d0);
    const float e1 = __expf(-sa.y * d1);
    const float e2 = __expf(-sa.z * d2);
    const float e3 = __expf(-sa.w * d3);
    const float e4 = __expf(-sb.x * d4);
    const float e5 = __expf(-sb.y * d5);
    const float e6 = __expf(-sb.z * d6);
    const float e7 = __expf(-sb.w * d7);
    const float f0 = e0 + 1e-10f, f1 = e1 + 1e-10f;
    const float f2 = e2 + 1e-10f, f3 = e3 + 1e-10f;
    const float f4 = e4 + 1e-10f, f5 = e5 + 1e-10f;
    const float f6 = e6 + 1e-10f, f7 = e7 + 1e-10f;

    // Segmented (16-lane) inclusive product scan of per-lane product
    float p = ((f0 * f1) * (f2 * f3)) * ((f4 * f5) * (f6 * f7));
    #pragma unroll
    for (int off = 1; off < 16; off <<= 1) {
        const float q = __shfl_up(p, off);
        if (seg >= off) p *= q;
    }
    float excl = __shfl_up(p, 1);                  // exclusive prefix
    if (seg == 0) excl = 1.0f;

    const float T0 = excl;
    const float T1 = T0 * f0;
    const float T2 = T1 * f1;
    const float T3 = T2 * f2;
    const float T4 = T3 * f3;
    const float T5 = T4 * f4;
    const float T6 = T5 * f5;
    const float T7 = T6 * f6;
    const float w0 = T0 * (1.0f - e0);
    const float w1 = T1 * (1.0f - e1);
    const float w2 = T2 * (1.0f - e2);
    const float w3 = T3 * (1.0f - e3);
    const float w4 = T4 * (1.0f - e4);
    const float w5 = T5 * (1.0f - e5);
    const float w6 = T6 * (1.0f - e6);
    const float w7 = T7 * (1.0f - e7);

    *(float4*)(out_w + base)     = make_float4(w0, w1, w2, w3);
    *(float4*)(out_w + base + 4) = make_float4(w4, w5, w6, w7);

    // Per-lane partials
    float cr  = w0 * q0.x + w1 * q0.w + w2 * q1.z + w3 * q2.y
              + w4 * q3.x + w5 * q3.w + w6 * q4.z + w7 * q5.y;
    float cg  = w0 * q0.y + w1 * q1.x + w2 * q1.w + w3 * q2.z
              + w4 * q3.y + w5 * q4.x + w6 * q4.w + w7 * q5.z;
    float cb  = w0 * q0.z + w1 * q1.y + w2 * q2.x + w3 * q2.w
              + w4 * q3.z + w5 * q4.y + w6 * q5.x + w7 * q5.w;
    float dep = w0 * ta.x + w1 * ta.y + w2 * ta.z + w3 * ta.w
              + w4 * tb.x + w5 * tb.y + w6 * tb.z + w7 * tb.w;
    float acc = (w0 + w1 + w2 + w3) + (w4 + w5 + w6 + w7);

    // Butterfly reduce within the 16-lane segment
    #pragma unroll
    for (int off = 8; off; off >>= 1) {
        cr  += __shfl_xor(cr,  off);
        cg  += __shfl_xor(cg,  off);
        cb  += __shfl_xor(cb,  off);
        dep += __shfl_xor(dep, off);
        acc += __shfl_xor(acc, off);
    }

    if (seg == 0) {
        out_rgb[ray * 3 + 0] = cr;
        out_rgb[ray * 3 + 1] = cg;
        out_rgb[ray * 3 + 2] = cb;
        out_depth[ray] = dep;
        out_acc[ray]   = acc;
    }
}
}  // namespace

extern "C" void kernel_launch(void* const* d_in, const int* in_sizes, int n_in,
                              void* d_out, int out_size, void* d_ws, size_t ws_size,
                              hipStream_t stream) {
    const float* dens  = (const float*)d_in[0];  // [B,N,S,1]
    const float* rgbs  = (const float*)d_in[1];  // [B,N,S,3]
    const float* tvals = (const float*)d_in[2];  // [B,N,S]

    float* out       = (float*)d_out;
    float* out_rgb   = out;                              // B*N*3
    float* out_w     = out_rgb + (long)kRays * 3;        // B*N*S
    float* out_depth = out_w + (long)kRays * kS;         // B*N
    float* out_acc   = out_depth + kRays;                // B*N

    const dim3 grid(kRays / kRaysPerBlock);
    const dim3 block(256);
    hipLaunchKernelGGL(volrender_kernel, grid, block, 0, stream,
                       dens, rgbs, tvals, out_rgb, out_w, out_depth, out_acc);
}

// Round 6
// 32.995 us; speedup vs baseline: 1.0367x; 1.0367x over previous
//
#include <hip/hip_runtime.h>

// Volume rendering (NeRF-style) for B=8, N=8192, S=128.
// One 16-lane segment per ray (4 rays/wave); lane owns 8 consecutive
// samples -> pure float4 traffic. Segmented 16-lane shuffle scan for the
// exclusive cumprod of (exp(-sigma*delta)+EPS).
// Best measured variant (33.07 us ~ 5.9 TB/s effective on 193.5 MB).

namespace {
constexpr int kB = 8;
constexpr int kN = 8192;
constexpr int kS = 128;
constexpr int kRays = kB * kN;          // 65536
constexpr int kWavesPerBlock = 4;       // block = 256 threads, 16 rays/block

typedef float f32x4 __attribute__((ext_vector_type(4)));

__global__ __launch_bounds__(256) void volrender_kernel(
    const float* __restrict__ dens,     // [rays, S]
    const float* __restrict__ rgbs,     // [rays, S, 3]
    const float* __restrict__ tvals,    // [rays, S]
    float* __restrict__ out_rgb,        // [rays, 3]
    float* __restrict__ out_w,          // [rays, S]
    float* __restrict__ out_depth,      // [rays]
    float* __restrict__ out_acc)        // [rays]
{
    const int lane = threadIdx.x & 63;
    const int wave = threadIdx.x >> 6;
    const int seg  = lane & 15;                   // lane within ray segment
    const int ray  = (blockIdx.x * kWavesPerBlock + wave) * 4 + (lane >> 4);

    const int base = ray * kS + seg * 8;          // first of this lane's 8 samples

    const float4 ta = *(const float4*)(tvals + base);
    const float4 tb = *(const float4*)(tvals + base + 4);
    const float4 sa = *(const float4*)(dens  + base);
    const float4 sb = *(const float4*)(dens  + base + 4);
    const float* rp = rgbs + ray * kS * 3 + seg * 24;
    const float4 q0 = *(const float4*)(rp + 0);
    const float4 q1 = *(const float4*)(rp + 4);
    const float4 q2 = *(const float4*)(rp + 8);
    const float4 q3 = *(const float4*)(rp + 12);
    const float4 q4 = *(const float4*)(rp + 16);
    const float4 q5 = *(const float4*)(rp + 20);

    // deltas; last sample of each ray -> 1e10
    const float t_next = __shfl_down(ta.x, 1);    // next lane's first t
    const float d0 = ta.y - ta.x;
    const float d1 = ta.z - ta.y;
    const float d2 = ta.w - ta.z;
    const float d3 = tb.x - ta.w;
    const float d4 = tb.y - tb.x;
    const float d5 = tb.z - tb.y;
    const float d6 = tb.w - tb.z;
    const float d7 = (seg == 15) ? 1e10f : (t_next - tb.w);

    // e = exp(-sigma*delta); alpha = 1-e; cumprod factor f = e + EPS
    const float e0 = __expf(-sa.x * d0);
    const float e1 = __expf(-sa.y * d1);
    const float e2 = __expf(-sa.z * d2);
    const float e3 = __expf(-sa.w * d3);
    const float e4 = __expf(-sb.x * d4);
    const float e5 = __expf(-sb.y * d5);
    const float e6 = __expf(-sb.z * d6);
    const float e7 = __expf(-sb.w * d7);
    const float f0 = e0 + 1e-10f, f1 = e1 + 1e-10f;
    const float f2 = e2 + 1e-10f, f3 = e3 + 1e-10f;
    const float f4 = e4 + 1e-10f, f5 = e5 + 1e-10f;
    const float f6 = e6 + 1e-10f, f7 = e7 + 1e-10f;

    // Segmented (16-lane) inclusive product scan of per-lane product
    float p = ((f0 * f1) * (f2 * f3)) * ((f4 * f5) * (f6 * f7));
    #pragma unroll
    for (int off = 1; off < 16; off <<= 1) {
        const float q = __shfl_up(p, off);
        if (seg >= off) p *= q;
    }
    float excl = __shfl_up(p, 1);                 // exclusive prefix
    if (seg == 0) excl = 1.0f;

    const float T0 = excl;
    const float T1 = T0 * f0;
    const float T2 = T1 * f1;
    const float T3 = T2 * f2;
    const float T4 = T3 * f3;
    const float T5 = T4 * f4;
    const float T6 = T5 * f5;
    const float T7 = T6 * f6;
    const float w0 = T0 * (1.0f - e0);
    const float w1 = T1 * (1.0f - e1);
    const float w2 = T2 * (1.0f - e2);
    const float w3 = T3 * (1.0f - e3);
    const float w4 = T4 * (1.0f - e4);
    const float w5 = T5 * (1.0f - e5);
    const float w6 = T6 * (1.0f - e6);
    const float w7 = T7 * (1.0f - e7);

    // Non-temporal stores: weights are write-only here
    f32x4 wa = {w0, w1, w2, w3};
    f32x4 wb = {w4, w5, w6, w7};
    __builtin_nontemporal_store(wa, (f32x4*)(out_w + base));
    __builtin_nontemporal_store(wb, (f32x4*)(out_w + base + 4));

    // Per-lane partials
    float cr  = w0 * q0.x + w1 * q0.w + w2 * q1.z + w3 * q2.y
              + w4 * q3.x + w5 * q3.w + w6 * q4.z + w7 * q5.y;
    float cg  = w0 * q0.y + w1 * q1.x + w2 * q1.w + w3 * q2.z
              + w4 * q3.y + w5 * q4.x + w6 * q4.w + w7 * q5.z;
    float cb  = w0 * q0.z + w1 * q1.y + w2 * q2.x + w3 * q2.w
              + w4 * q3.z + w5 * q4.y + w6 * q5.x + w7 * q5.w;
    float dep = w0 * ta.x + w1 * ta.y + w2 * ta.z + w3 * ta.w
              + w4 * tb.x + w5 * tb.y + w6 * tb.z + w7 * tb.w;
    float acc = (w0 + w1 + w2 + w3) + (w4 + w5 + w6 + w7);

    // Butterfly reduce within the 16-lane segment
    #pragma unroll
    for (int off = 8; off; off >>= 1) {
        cr  += __shfl_xor(cr,  off);
        cg  += __shfl_xor(cg,  off);
        cb  += __shfl_xor(cb,  off);
        dep += __shfl_xor(dep, off);
        acc += __shfl_xor(acc, off);
    }

    if (seg == 0) {
        out_rgb[ray * 3 + 0] = cr;
        out_rgb[ray * 3 + 1] = cg;
        out_rgb[ray * 3 + 2] = cb;
        out_depth[ray] = dep;
        out_acc[ray]   = acc;
    }
}
}  // namespace

extern "C" void kernel_launch(void* const* d_in, const int* in_sizes, int n_in,
                              void* d_out, int out_size, void* d_ws, size_t ws_size,
                              hipStream_t stream) {
    const float* dens  = (const float*)d_in[0];  // [B,N,S,1]
    const float* rgbs  = (const float*)d_in[1];  // [B,N,S,3]
    const float* tvals = (const float*)d_in[2];  // [B,N,S]

    float* out       = (float*)d_out;
    float* out_rgb   = out;                              // B*N*3
    float* out_w     = out_rgb + (long)kRays * 3;        // B*N*S
    float* out_depth = out_w + (long)kRays * kS;         // B*N
    float* out_acc   = out_depth + kRays;                // B*N

    const dim3 grid(kRays / (kWavesPerBlock * 4));
    const dim3 block(kWavesPerBlock * 64);
    hipLaunchKernelGGL(volrender_kernel, grid, block, 0, stream,
                       dens, rgbs, tvals, out_rgb, out_w, out_depth, out_acc);
}